// Round 1
// baseline (891.896 us; speedup 1.0000x reference)
//
#include <hip/hip_runtime.h>
#include <hip/hip_bf16.h>
#include <math.h>

#define B_ 4
#define P_ 2048
#define D_ 768
#define H_ 12
#define DFF_ 3072

typedef __attribute__((ext_vector_type(8))) short bf16x8;
typedef __attribute__((ext_vector_type(4))) float f32x4;

static __device__ __forceinline__ short f2bf(float f) {
  union { float f; unsigned u; } z; z.f = f;
  unsigned r = z.u + 0x7fffu + ((z.u >> 16) & 1u);
  return (short)(r >> 16);
}

__global__ void cvt_kernel(const float* __restrict__ in, short* __restrict__ out, int n) {
  int i = blockIdx.x * 256 + threadIdx.x;
  if (i < n) out[i] = f2bf(in[i]);
}

// One block per row of 768. Reads f32, writes bf16 normalized row.
__global__ __launch_bounds__(256) void ln_kernel(const float* __restrict__ in,
                                                 const float* __restrict__ g,
                                                 const float* __restrict__ be,
                                                 short* __restrict__ out) {
  int row = blockIdx.x, tid = threadIdx.x;
  const float* xr = in + (size_t)row * D_;
  float v0 = xr[tid], v1 = xr[tid + 256], v2 = xr[tid + 512];
  float s = v0 + v1 + v2;
  float ss = v0 * v0 + v1 * v1 + v2 * v2;
#pragma unroll
  for (int d = 1; d < 64; d <<= 1) {
    s += __shfl_xor(s, d, 64);
    ss += __shfl_xor(ss, d, 64);
  }
  __shared__ float red[8];
  int w = tid >> 6;
  if ((tid & 63) == 0) { red[w] = s; red[4 + w] = ss; }
  __syncthreads();
  s = red[0] + red[1] + red[2] + red[3];
  ss = red[4] + red[5] + red[6] + red[7];
  float mu = s * (1.0f / D_);
  float rstd = rsqrtf(ss * (1.0f / D_) - mu * mu + 1e-3f);
  short* orow = out + (size_t)row * D_;
  orow[tid]       = f2bf((v0 - mu) * rstd * g[tid]       + be[tid]);
  orow[tid + 256] = f2bf((v1 - mu) * rstd * g[tid + 256] + be[tid + 256]);
  orow[tid + 512] = f2bf((v2 - mu) * rstd * g[tid + 512] + be[tid + 512]);
}

// C[M,N] = A[M,K](bf16) @ Bw[K,N](bf16) + bias, with epilogue:
// EPI=0: -> bf16 out   EPI=1: gelu -> bf16 out   EPI=2: *0.9 + resid -> f32 out
template <int EPI>
__global__ __launch_bounds__(256) void gemm_kernel(
    const short* __restrict__ A, const short* __restrict__ Bw,
    const float* __restrict__ bias, short* __restrict__ out_bf,
    float* __restrict__ out_f, const float* __restrict__ resid,
    int M, int N, int K) {
  alignas(16) __shared__ short a_lds[64 * 40];
  alignas(16) __shared__ short b_lds[64 * 40];
  int tid = threadIdx.x;
  int wv = tid >> 6, lane = tid & 63;
  int g = lane >> 4, r = lane & 15;
  int m0 = blockIdx.x * 64, n0 = blockIdx.y * 64;
  f32x4 acc[4] = {};
  int arow = tid >> 2, aseg = tid & 3;     // A tile: 64 rows x 32 k
  int bk = tid >> 3, bn = (tid & 7) * 8;   // B tile: 32 k x 64 n
  for (int k0 = 0; k0 < K; k0 += 32) {
    __syncthreads();
    bf16x8 av = *reinterpret_cast<const bf16x8*>(A + (size_t)(m0 + arow) * K + k0 + aseg * 8);
    *reinterpret_cast<bf16x8*>(&a_lds[arow * 40 + aseg * 8]) = av;
    bf16x8 bv = *reinterpret_cast<const bf16x8*>(Bw + (size_t)(k0 + bk) * N + n0 + bn);
#pragma unroll
    for (int j = 0; j < 8; ++j) b_lds[(bn + j) * 40 + bk] = bv[j];  // store transposed [n][k]
    __syncthreads();
    bf16x8 af = *reinterpret_cast<const bf16x8*>(&a_lds[(wv * 16 + r) * 40 + g * 8]);
#pragma unroll
    for (int cf = 0; cf < 4; ++cf) {
      bf16x8 bf_ = *reinterpret_cast<const bf16x8*>(&b_lds[(cf * 16 + r) * 40 + g * 8]);
      acc[cf] = __builtin_amdgcn_mfma_f32_16x16x32_bf16(af, bf_, acc[cf], 0, 0, 0);
    }
  }
#pragma unroll
  for (int cf = 0; cf < 4; ++cf) {
    int col = n0 + cf * 16 + r;
    float bvs = bias[col];
#pragma unroll
    for (int j = 0; j < 4; ++j) {
      int row = m0 + wv * 16 + g * 4 + j;
      float v = acc[cf][j] + bvs;
      size_t idx = (size_t)row * N + col;
      if (EPI == 0) {
        out_bf[idx] = f2bf(v);
      } else if (EPI == 1) {
        v = 0.5f * v * (1.0f + erff(v * 0.70710678118654752f));
        out_bf[idx] = f2bf(v);
      } else {
        out_f[idx] = v * 0.9f + resid[idx];
      }
    }
  }
}

// Flash attention: grid (P/64, B*H). 4 waves, each owns 16 q rows.
// qkv bf16 [B,P,3D]; writes x2 = 0.9*attn_out + x (f32).
__global__ __launch_bounds__(256) void attn_kernel(const short* __restrict__ qkv,
                                                   const float* __restrict__ x,
                                                   float* __restrict__ x2) {
  alignas(16) __shared__ short k_lds[64 * 72];
  alignas(16) __shared__ short v_lds[64 * 72];
  alignas(16) __shared__ short p_lds[4 * 16 * 72];
  int tid = threadIdx.x, wv = tid >> 6, lane = tid & 63;
  int g = lane >> 4, r = lane & 15;
  int qt = blockIdx.x, bh = blockIdx.y;
  int b = bh / H_, h = bh % H_;
  const int TD = 3 * D_;
  int qrow0 = qt * 64 + wv * 16;
  bf16x8 qf[2];
#pragma unroll
  for (int kb = 0; kb < 2; ++kb)
    qf[kb] = *reinterpret_cast<const bf16x8*>(
        qkv + (size_t)(b * P_ + qrow0 + r) * TD + h * 64 + kb * 32 + g * 8);
  f32x4 acc_o[4] = {};
  float m_run[4], l_run[4];
#pragma unroll
  for (int j = 0; j < 4; ++j) { m_run[j] = -1e30f; l_run[j] = 0.0f; }
  int lrow = tid >> 2, lseg = tid & 3;
  for (int kc = 0; kc < P_; kc += 64) {
    __syncthreads();
    {
      size_t base = (size_t)(b * P_ + kc + lrow) * TD + h * 64 + lseg * 16;
      *reinterpret_cast<bf16x8*>(&k_lds[lrow * 72 + lseg * 16]) =
          *reinterpret_cast<const bf16x8*>(qkv + base + D_);
      *reinterpret_cast<bf16x8*>(&k_lds[lrow * 72 + lseg * 16 + 8]) =
          *reinterpret_cast<const bf16x8*>(qkv + base + D_ + 8);
      *reinterpret_cast<bf16x8*>(&v_lds[lrow * 72 + lseg * 16]) =
          *reinterpret_cast<const bf16x8*>(qkv + base + 2 * D_);
      *reinterpret_cast<bf16x8*>(&v_lds[lrow * 72 + lseg * 16 + 8]) =
          *reinterpret_cast<const bf16x8*>(qkv + base + 2 * D_ + 8);
    }
    __syncthreads();
    f32x4 sc[4];
#pragma unroll
    for (int cf = 0; cf < 4; ++cf) {
      bf16x8 kf0 = *reinterpret_cast<const bf16x8*>(&k_lds[(cf * 16 + r) * 72 + g * 8]);
      bf16x8 kf1 = *reinterpret_cast<const bf16x8*>(&k_lds[(cf * 16 + r) * 72 + 32 + g * 8]);
      f32x4 s = {};
      s = __builtin_amdgcn_mfma_f32_16x16x32_bf16(qf[0], kf0, s, 0, 0, 0);
      s = __builtin_amdgcn_mfma_f32_16x16x32_bf16(qf[1], kf1, s, 0, 0, 0);
      sc[cf] = s;
    }
    float pv[4][4];
#pragma unroll
    for (int j = 0; j < 4; ++j) {
      float s0 = sc[0][j] * 0.125f, s1 = sc[1][j] * 0.125f;
      float s2 = sc[2][j] * 0.125f, s3 = sc[3][j] * 0.125f;
      float mt = fmaxf(fmaxf(s0, s1), fmaxf(s2, s3));
#pragma unroll
      for (int d = 1; d < 16; d <<= 1) mt = fmaxf(mt, __shfl_xor(mt, d, 64));
      float mn = fmaxf(m_run[j], mt);
      float corr = __expf(m_run[j] - mn);
      m_run[j] = mn;
      float p0 = __expf(s0 - mn), p1 = __expf(s1 - mn);
      float p2 = __expf(s2 - mn), p3 = __expf(s3 - mn);
      pv[0][j] = p0; pv[1][j] = p1; pv[2][j] = p2; pv[3][j] = p3;
      float ls = p0 + p1 + p2 + p3;
#pragma unroll
      for (int d = 1; d < 16; d <<= 1) ls += __shfl_xor(ls, d, 64);
      l_run[j] = l_run[j] * corr + ls;
      acc_o[0][j] *= corr; acc_o[1][j] *= corr;
      acc_o[2][j] *= corr; acc_o[3][j] *= corr;
    }
#pragma unroll
    for (int cf = 0; cf < 4; ++cf)
#pragma unroll
      for (int j = 0; j < 4; ++j)
        p_lds[wv * 1152 + (g * 4 + j) * 72 + cf * 16 + r] = f2bf(pv[cf][j]);
    bf16x8 pf0 = *reinterpret_cast<const bf16x8*>(&p_lds[wv * 1152 + r * 72 + g * 8]);
    bf16x8 pf1 = *reinterpret_cast<const bf16x8*>(&p_lds[wv * 1152 + r * 72 + 32 + g * 8]);
#pragma unroll
    for (int cf = 0; cf < 4; ++cf) {
#pragma unroll
      for (int kb = 0; kb < 2; ++kb) {
        bf16x8 vf;
#pragma unroll
        for (int j = 0; j < 8; ++j) vf[j] = v_lds[(kb * 32 + g * 8 + j) * 72 + cf * 16 + r];
        acc_o[cf] = __builtin_amdgcn_mfma_f32_16x16x32_bf16(kb ? pf1 : pf0, vf, acc_o[cf], 0, 0, 0);
      }
    }
  }
#pragma unroll
  for (int cf = 0; cf < 4; ++cf) {
    int col = h * 64 + cf * 16 + r;
#pragma unroll
    for (int j = 0; j < 4; ++j) {
      int row = qrow0 + g * 4 + j;
      size_t idx = (size_t)(b * P_ + row) * D_ + col;
      x2[idx] = (acc_o[cf][j] / l_run[j]) * 0.9f + x[idx];
    }
  }
}

extern "C" void kernel_launch(void* const* d_in, const int* in_sizes, int n_in,
                              void* d_out, int out_size, void* d_ws, size_t ws_size,
                              hipStream_t stream) {
  const float* x     = (const float*)d_in[0];
  const float* ln1_g = (const float*)d_in[1];
  const float* ln1_b = (const float*)d_in[2];
  const float* w_qkv = (const float*)d_in[3];
  const float* b_qkv = (const float*)d_in[4];
  const float* ln2_g = (const float*)d_in[5];
  const float* ln2_b = (const float*)d_in[6];
  const float* w1    = (const float*)d_in[7];
  const float* b1    = (const float*)d_in[8];
  const float* w2    = (const float*)d_in[9];
  const float* b2    = (const float*)d_in[10];
  float* out = (float*)d_out;
  char* ws = (char*)d_ws;

  short* wqkv_bf = (short*)(ws);                 // 768*2304*2  = 3,538,944
  short* w1_bf   = (short*)(ws + 3538944);       // 768*3072*2  = 4,718,592
  short* w2_bf   = (short*)(ws + 8257536);       // 3072*768*2  = 4,718,592
  short* h_bf    = (short*)(ws + 12976128);      // 8192*768*2  = 12,582,912
  short* qkv_bf  = (short*)(ws + 25559040);      // 8192*2304*2 = 37,748,736
  short* a1_bf   = qkv_bf;                       // reused: 8192*3072*2 = 50,331,648
  // total ws usage: 75,890,688 bytes. x2 lives in d_out (f32).

  const int R = B_ * P_;  // 8192 rows

  cvt_kernel<<<(768 * 2304 + 255) / 256, 256, 0, stream>>>(w_qkv, wqkv_bf, 768 * 2304);
  cvt_kernel<<<(768 * 3072 + 255) / 256, 256, 0, stream>>>(w1, w1_bf, 768 * 3072);
  cvt_kernel<<<(3072 * 768 + 255) / 256, 256, 0, stream>>>(w2, w2_bf, 3072 * 768);

  ln_kernel<<<R, 256, 0, stream>>>(x, ln1_g, ln1_b, h_bf);

  {
    dim3 grid(R / 64, 2304 / 64);
    gemm_kernel<0><<<grid, 256, 0, stream>>>(h_bf, wqkv_bf, b_qkv, qkv_bf, nullptr, nullptr,
                                             R, 2304, 768);
  }
  {
    dim3 grid(P_ / 64, B_ * H_);
    attn_kernel<<<grid, 256, 0, stream>>>(qkv_bf, x, out);
  }
  ln_kernel<<<R, 256, 0, stream>>>(out, ln2_g, ln2_b, h_bf);
  {
    dim3 grid(R / 64, 3072 / 64);
    gemm_kernel<1><<<grid, 256, 0, stream>>>(h_bf, w1_bf, b1, a1_bf, nullptr, nullptr,
                                             R, 3072, 768);
  }
  {
    dim3 grid(R / 64, 768 / 64);
    gemm_kernel<2><<<grid, 256, 0, stream>>>(a1_bf, w2_bf, b2, nullptr, out, out,
                                             R, 768, 3072);
  }
}

// Round 3
// 460.705 us; speedup vs baseline: 1.9359x; 1.9359x over previous
//
#include <hip/hip_runtime.h>
#include <hip/hip_bf16.h>
#include <math.h>

#define B_ 4
#define P_ 2048
#define D_ 768
#define H_ 12

typedef __attribute__((ext_vector_type(8))) short bf16x8;
typedef __attribute__((ext_vector_type(4))) float f32x4;

static __device__ __forceinline__ short f2bf(float f) {
  union { float f; unsigned u; } z; z.f = f;
  unsigned r = z.u + 0x7fffu + ((z.u >> 16) & 1u);
  return (short)(r >> 16);
}

static __device__ __forceinline__ void gll16(const void* g, void* l) {
  __builtin_amdgcn_global_load_lds(
      (const __attribute__((address_space(1))) void*)g,
      (__attribute__((address_space(3))) void*)l, 16, 0, 0);
}

// V-LDS column swizzle: makes both transposed b16 writes and b128 reads bank-ideal.
static __device__ __forceinline__ int vswz(int d) {
  return ((d & 7) ^ ((d >> 3) & 7)) << 3;
}

// Tiled transpose + fp32->bf16: out[N][K] = cvt(in[K][N])
__global__ __launch_bounds__(256) void tcvt_kernel(const float* __restrict__ in,
                                                   short* __restrict__ out, int K, int N) {
  __shared__ float t[32][33];
  int k0 = blockIdx.x * 32, n0 = blockIdx.y * 32;
  int tx = threadIdx.x & 31, ty = threadIdx.x >> 5;
#pragma unroll
  for (int i = 0; i < 4; ++i)
    t[ty + 8 * i][tx] = in[(size_t)(k0 + ty + 8 * i) * N + n0 + tx];
  __syncthreads();
#pragma unroll
  for (int i = 0; i < 4; ++i)
    out[(size_t)(n0 + ty + 8 * i) * K + k0 + tx] = f2bf(t[tx][ty + 8 * i]);
}

// One block per row of 768. Reads f32, writes bf16 normalized row.
__global__ __launch_bounds__(256) void ln_kernel(const float* __restrict__ in,
                                                 const float* __restrict__ g,
                                                 const float* __restrict__ be,
                                                 short* __restrict__ out) {
  int row = blockIdx.x, tid = threadIdx.x;
  const float* xr = in + (size_t)row * D_;
  float v0 = xr[tid], v1 = xr[tid + 256], v2 = xr[tid + 512];
  float s = v0 + v1 + v2;
  float ss = v0 * v0 + v1 * v1 + v2 * v2;
#pragma unroll
  for (int d = 1; d < 64; d <<= 1) {
    s += __shfl_xor(s, d, 64);
    ss += __shfl_xor(ss, d, 64);
  }
  __shared__ float red[8];
  int w = tid >> 6;
  if ((tid & 63) == 0) { red[w] = s; red[4 + w] = ss; }
  __syncthreads();
  s = red[0] + red[1] + red[2] + red[3];
  ss = red[4] + red[5] + red[6] + red[7];
  float mu = s * (1.0f / D_);
  float rstd = rsqrtf(ss * (1.0f / D_) - mu * mu + 1e-3f);
  short* orow = out + (size_t)row * D_;
  orow[tid]       = f2bf((v0 - mu) * rstd * g[tid]       + be[tid]);
  orow[tid + 256] = f2bf((v1 - mu) * rstd * g[tid + 256] + be[tid + 256]);
  orow[tid + 512] = f2bf((v2 - mu) * rstd * g[tid + 512] + be[tid + 512]);
}

// C[M,N] = A[M,K](bf16) @ Bt[N,K]^T(bf16) + bias. 128x128 tile, BK=32 (m97 structure).
// EPI=0: ->bf16  EPI=1: gelu->bf16  EPI=2: *0.9+resid ->f32
template <int EPI>
__global__ __launch_bounds__(256, 3) void gemm128(
    const short* __restrict__ A, const short* __restrict__ Bt,
    const float* __restrict__ bias, short* __restrict__ out_bf,
    float* __restrict__ out_f, const float* __restrict__ resid,
    int M, int N, int K) {
  alignas(16) __shared__ short a_lds[128 * 32];
  alignas(16) __shared__ short b_lds[128 * 32];
  const int tid = threadIdx.x;
  const int wv = tid >> 6, lane = tid & 63;
  const int wm = wv >> 1, wn = wv & 1;
  const int g = lane >> 4, r = lane & 15;
  const int m0 = blockIdx.x * 128, n0 = blockIdx.y * 128;
  const int srow = lane >> 2, sseg = lane & 3;
  f32x4 acc[4][4] = {};
  const short* aptr = A + (size_t)(m0 + wv * 16 + srow) * K + sseg * 8;
  const short* bptr = Bt + (size_t)(n0 + wv * 16 + srow) * K + sseg * 8;
  short* alds0 = &a_lds[(wv * 16) * 32];
  short* blds0 = &b_lds[(wv * 16) * 32];
  for (int k0 = 0; k0 < K; k0 += 32) {
    __syncthreads();
    gll16(aptr + k0, alds0);
    gll16(aptr + k0 + (size_t)64 * K, alds0 + 64 * 32);
    gll16(bptr + k0, blds0);
    gll16(bptr + k0 + (size_t)64 * K, blds0 + 64 * 32);
    __syncthreads();
    bf16x8 af[4], bfr[4];
#pragma unroll
    for (int i = 0; i < 4; ++i)
      af[i] = *reinterpret_cast<const bf16x8*>(&a_lds[(wm * 64 + i * 16 + r) * 32 + g * 8]);
#pragma unroll
    for (int i = 0; i < 4; ++i)
      bfr[i] = *reinterpret_cast<const bf16x8*>(&b_lds[(wn * 64 + i * 16 + r) * 32 + g * 8]);
#pragma unroll
    for (int i = 0; i < 4; ++i)
#pragma unroll
      for (int jn = 0; jn < 4; ++jn)
        acc[i][jn] = __builtin_amdgcn_mfma_f32_16x16x32_bf16(af[i], bfr[jn], acc[i][jn], 0, 0, 0);
  }
#pragma unroll
  for (int i = 0; i < 4; ++i) {
#pragma unroll
    for (int jn = 0; jn < 4; ++jn) {
      int col = n0 + wn * 64 + jn * 16 + r;
      float bb = bias[col];
#pragma unroll
      for (int jj = 0; jj < 4; ++jj) {
        int row = m0 + wm * 64 + i * 16 + g * 4 + jj;
        float v = acc[i][jn][jj] + bb;
        size_t idx = (size_t)row * N + col;
        if (EPI == 0) {
          out_bf[idx] = f2bf(v);
        } else if (EPI == 1) {
          v = 0.5f * v * (1.0f + erff(v * 0.70710678118654752f));
          out_bf[idx] = f2bf(v);
        } else {
          out_f[idx] = v * 0.9f + resid[idx];
        }
      }
    }
  }
}

// Flash attention: grid (P/128, B*H). 4 waves, each owns 32 q rows (2 m-frags).
// V staged transposed+swizzled in LDS so PV B-fragments are vector reads.
__global__ __launch_bounds__(256, 3) void attn_kernel(const short* __restrict__ qkv,
                                                      const float* __restrict__ x,
                                                      float* __restrict__ x2) {
  alignas(16) __shared__ short k_lds[64 * 72];
  alignas(16) __shared__ short vt_lds[64 * 64];
  alignas(16) __shared__ short p_lds[4][32 * 72];
  const int tid = threadIdx.x, wv = tid >> 6, lane = tid & 63;
  const int g = lane >> 4, r = lane & 15;
  const int b = blockIdx.y / H_, h = blockIdx.y % H_;
  const int TD = 3 * D_;
  const int qrow0 = blockIdx.x * 128 + wv * 32;
  bf16x8 qf[2][2];
#pragma unroll
  for (int mf = 0; mf < 2; ++mf)
#pragma unroll
    for (int kb = 0; kb < 2; ++kb)
      qf[mf][kb] = *reinterpret_cast<const bf16x8*>(
          qkv + (size_t)(b * P_ + qrow0 + mf * 16 + r) * TD + h * 64 + kb * 32 + g * 8);
  f32x4 acc[2][4] = {};
  float m_run[2][4], l_run[2][4];
#pragma unroll
  for (int mf = 0; mf < 2; ++mf)
#pragma unroll
    for (int j = 0; j < 4; ++j) { m_run[mf][j] = -1e30f; l_run[mf][j] = 0.0f; }
  const int lrow = tid >> 2, lseg = tid & 3;
  short* p_w = &p_lds[wv][0];
  for (int kc = 0; kc < P_; kc += 64) {
    // prefetch K/V rows to registers before the barrier (overlap with prev compute)
    const short* src = qkv + (size_t)(b * P_ + kc + lrow) * TD + D_ + h * 64 + lseg * 16;
    bf16x8 kv0 = *reinterpret_cast<const bf16x8*>(src);
    bf16x8 kv1 = *reinterpret_cast<const bf16x8*>(src + 8);
    bf16x8 vv0 = *reinterpret_cast<const bf16x8*>(src + D_);
    bf16x8 vv1 = *reinterpret_cast<const bf16x8*>(src + D_ + 8);
    __syncthreads();
    *reinterpret_cast<bf16x8*>(&k_lds[lrow * 72 + lseg * 16]) = kv0;
    *reinterpret_cast<bf16x8*>(&k_lds[lrow * 72 + lseg * 16 + 8]) = kv1;
#pragma unroll
    for (int j = 0; j < 8; ++j) {
      int d0 = lseg * 16 + j, d1 = d0 + 8;
      vt_lds[d0 * 64 + (lrow ^ vswz(d0))] = vv0[j];
      vt_lds[d1 * 64 + (lrow ^ vswz(d1))] = vv1[j];
    }
    __syncthreads();
    // QK^T
    f32x4 sc[2][4];
#pragma unroll
    for (int cf = 0; cf < 4; ++cf) {
      bf16x8 kf0 = *reinterpret_cast<const bf16x8*>(&k_lds[(cf * 16 + r) * 72 + g * 8]);
      bf16x8 kf1 = *reinterpret_cast<const bf16x8*>(&k_lds[(cf * 16 + r) * 72 + 32 + g * 8]);
#pragma unroll
      for (int mf = 0; mf < 2; ++mf) {
        f32x4 s = {};
        s = __builtin_amdgcn_mfma_f32_16x16x32_bf16(qf[mf][0], kf0, s, 0, 0, 0);
        s = __builtin_amdgcn_mfma_f32_16x16x32_bf16(qf[mf][1], kf1, s, 0, 0, 0);
        sc[mf][cf] = s;
      }
    }
    // online softmax; row q = mf*16 + g*4 + j lives across lanes r
#pragma unroll
    for (int mf = 0; mf < 2; ++mf) {
#pragma unroll
      for (int j = 0; j < 4; ++j) {
        float s0 = sc[mf][0][j] * 0.125f, s1 = sc[mf][1][j] * 0.125f;
        float s2 = sc[mf][2][j] * 0.125f, s3 = sc[mf][3][j] * 0.125f;
        float mt = fmaxf(fmaxf(s0, s1), fmaxf(s2, s3));
#pragma unroll
        for (int d = 1; d < 16; d <<= 1) mt = fmaxf(mt, __shfl_xor(mt, d, 64));
        float mn = fmaxf(m_run[mf][j], mt);
        float corr = __expf(m_run[mf][j] - mn);
        m_run[mf][j] = mn;
        float p0 = __expf(s0 - mn), p1 = __expf(s1 - mn);
        float p2 = __expf(s2 - mn), p3 = __expf(s3 - mn);
        float ls = p0 + p1 + p2 + p3;
#pragma unroll
        for (int d = 1; d < 16; d <<= 1) ls += __shfl_xor(ls, d, 64);
        l_run[mf][j] = l_run[mf][j] * corr + ls;
#pragma unroll
        for (int cf = 0; cf < 4; ++cf) acc[mf][cf][j] *= corr;
        int prow = (mf * 16 + g * 4 + j) * 72;
        p_w[prow + 0 + r]  = f2bf(p0);
        p_w[prow + 16 + r] = f2bf(p1);
        p_w[prow + 32 + r] = f2bf(p2);
        p_w[prow + 48 + r] = f2bf(p3);
      }
    }
    // PV: vector V fragments from swizzled vt_lds
    bf16x8 vf[4][2];
#pragma unroll
    for (int cf = 0; cf < 4; ++cf) {
      int d = cf * 16 + r;
      int sw = vswz(d);
      vf[cf][0] = *reinterpret_cast<const bf16x8*>(&vt_lds[d * 64 + ((g * 8) ^ sw)]);
      vf[cf][1] = *reinterpret_cast<const bf16x8*>(&vt_lds[d * 64 + ((32 + g * 8) ^ sw)]);
    }
#pragma unroll
    for (int mf = 0; mf < 2; ++mf) {
      bf16x8 pf0 = *reinterpret_cast<const bf16x8*>(&p_w[(mf * 16 + r) * 72 + g * 8]);
      bf16x8 pf1 = *reinterpret_cast<const bf16x8*>(&p_w[(mf * 16 + r) * 72 + 32 + g * 8]);
#pragma unroll
      for (int cf = 0; cf < 4; ++cf) {
        acc[mf][cf] = __builtin_amdgcn_mfma_f32_16x16x32_bf16(pf0, vf[cf][0], acc[mf][cf], 0, 0, 0);
        acc[mf][cf] = __builtin_amdgcn_mfma_f32_16x16x32_bf16(pf1, vf[cf][1], acc[mf][cf], 0, 0, 0);
      }
    }
  }
#pragma unroll
  for (int mf = 0; mf < 2; ++mf)
#pragma unroll
    for (int cf = 0; cf < 4; ++cf) {
      int col = h * 64 + cf * 16 + r;
#pragma unroll
      for (int j = 0; j < 4; ++j) {
        int row = qrow0 + mf * 16 + g * 4 + j;
        size_t idx = (size_t)(b * P_ + row) * D_ + col;
        x2[idx] = (acc[mf][cf][j] / l_run[mf][j]) * 0.9f + x[idx];
      }
    }
}

extern "C" void kernel_launch(void* const* d_in, const int* in_sizes, int n_in,
                              void* d_out, int out_size, void* d_ws, size_t ws_size,
                              hipStream_t stream) {
  const float* x     = (const float*)d_in[0];
  const float* ln1_g = (const float*)d_in[1];
  const float* ln1_b = (const float*)d_in[2];
  const float* w_qkv = (const float*)d_in[3];
  const float* b_qkv = (const float*)d_in[4];
  const float* ln2_g = (const float*)d_in[5];
  const float* ln2_b = (const float*)d_in[6];
  const float* w1    = (const float*)d_in[7];
  const float* b1    = (const float*)d_in[8];
  const float* w2    = (const float*)d_in[9];
  const float* b2    = (const float*)d_in[10];
  float* out = (float*)d_out;
  char* ws = (char*)d_ws;

  short* wqkv_t = (short*)(ws);                 // [2304][768]  = 3,538,944 B
  short* w1_t   = (short*)(ws + 3538944);       // [3072][768]  = 4,718,592 B
  short* w2_t   = (short*)(ws + 8257536);       // [768][3072]  = 4,718,592 B
  short* h_bf   = (short*)(ws + 12976128);      // [8192][768]  = 12,582,912 B
  short* qkv_bf = (short*)(ws + 25559040);      // [8192][2304] = 37,748,736 B
  short* a1_bf  = qkv_bf;                       // reused: [8192][3072] = 50,331,648 B

  const int R = B_ * P_;  // 8192 rows

  { dim3 g2(768 / 32, 2304 / 32);  tcvt_kernel<<<g2, 256, 0, stream>>>(w_qkv, wqkv_t, 768, 2304); }
  { dim3 g2(768 / 32, 3072 / 32);  tcvt_kernel<<<g2, 256, 0, stream>>>(w1, w1_t, 768, 3072); }
  { dim3 g2(3072 / 32, 768 / 32);  tcvt_kernel<<<g2, 256, 0, stream>>>(w2, w2_t, 3072, 768); }

  ln_kernel<<<R, 256, 0, stream>>>(x, ln1_g, ln1_b, h_bf);

  {
    dim3 grid(R / 128, 2304 / 128);
    gemm128<0><<<grid, 256, 0, stream>>>(h_bf, wqkv_t, b_qkv, qkv_bf, nullptr, nullptr,
                                         R, 2304, 768);
  }
  {
    dim3 grid(P_ / 128, B_ * H_);
    attn_kernel<<<grid, 256, 0, stream>>>(qkv_bf, x, out);
  }
  ln_kernel<<<R, 256, 0, stream>>>(out, ln2_g, ln2_b, h_bf);
  {
    dim3 grid(R / 128, 3072 / 128);
    gemm128<1><<<grid, 256, 0, stream>>>(h_bf, w1_t, b1, a1_bf, nullptr, nullptr,
                                         R, 3072, 768);
  }
  {
    dim3 grid(R / 128, 768 / 128);
    gemm128<2><<<grid, 256, 0, stream>>>(a1_bf, w2_t, b2, nullptr, out, out,
                                         R, 768, 3072);
  }
}

// Round 4
// 397.305 us; speedup vs baseline: 2.2449x; 1.1596x over previous
//
#include <hip/hip_runtime.h>
#include <hip/hip_bf16.h>
#include <math.h>

#define B_ 4
#define P_ 2048
#define D_ 768
#define H_ 12

typedef __attribute__((ext_vector_type(8))) short bf16x8;
typedef __attribute__((ext_vector_type(4))) float f32x4;

static __device__ __forceinline__ short f2bf(float f) {
  union { float f; unsigned u; } z; z.f = f;
  unsigned r = z.u + 0x7fffu + ((z.u >> 16) & 1u);
  return (short)(r >> 16);
}

static __device__ __forceinline__ float bf2f(short s) {
  union { unsigned u; float f; } z;
  z.u = ((unsigned)(unsigned short)s) << 16;
  return z.f;
}

static __device__ __forceinline__ void gll16(const void* g, void* l) {
  __builtin_amdgcn_global_load_lds(
      (const __attribute__((address_space(1))) void*)g,
      (__attribute__((address_space(3))) void*)l, 16, 0, 0);
}

// V-LDS column swizzle: makes both transposed b16 writes and b128 reads bank-ideal.
static __device__ __forceinline__ int vswz(int d) {
  return ((d & 7) ^ ((d >> 3) & 7)) << 3;
}

// Tiled transpose + fp32->bf16: out[N][K] = cvt(in[K][N])
__global__ __launch_bounds__(256) void tcvt_kernel(const float* __restrict__ in,
                                                   short* __restrict__ out, int K, int N) {
  __shared__ float t[32][33];
  int k0 = blockIdx.x * 32, n0 = blockIdx.y * 32;
  int tx = threadIdx.x & 31, ty = threadIdx.x >> 5;
#pragma unroll
  for (int i = 0; i < 4; ++i)
    t[ty + 8 * i][tx] = in[(size_t)(k0 + ty + 8 * i) * N + n0 + tx];
  __syncthreads();
#pragma unroll
  for (int i = 0; i < 4; ++i)
    out[(size_t)(n0 + ty + 8 * i) * K + k0 + tx] = f2bf(t[tx][ty + 8 * i]);
}

// One block per row of 768. Reads f32, writes bf16 normalized row.
__global__ __launch_bounds__(256) void ln_kernel(const float* __restrict__ in,
                                                 const float* __restrict__ g,
                                                 const float* __restrict__ be,
                                                 short* __restrict__ out) {
  int row = blockIdx.x, tid = threadIdx.x;
  const float* xr = in + (size_t)row * D_;
  float v0 = xr[tid], v1 = xr[tid + 256], v2 = xr[tid + 512];
  float s = v0 + v1 + v2;
  float ss = v0 * v0 + v1 * v1 + v2 * v2;
#pragma unroll
  for (int d = 1; d < 64; d <<= 1) {
    s += __shfl_xor(s, d, 64);
    ss += __shfl_xor(ss, d, 64);
  }
  __shared__ float red[8];
  int w = tid >> 6;
  if ((tid & 63) == 0) { red[w] = s; red[4 + w] = ss; }
  __syncthreads();
  s = red[0] + red[1] + red[2] + red[3];
  ss = red[4] + red[5] + red[6] + red[7];
  float mu = s * (1.0f / D_);
  float rstd = rsqrtf(ss * (1.0f / D_) - mu * mu + 1e-3f);
  short* orow = out + (size_t)row * D_;
  orow[tid]       = f2bf((v0 - mu) * rstd * g[tid]       + be[tid]);
  orow[tid + 256] = f2bf((v1 - mu) * rstd * g[tid + 256] + be[tid + 256]);
  orow[tid + 512] = f2bf((v2 - mu) * rstd * g[tid + 512] + be[tid + 512]);
}

// C[M,N] = A[M,K](bf16) @ Bt[N,K]^T(bf16) + bias. 128x128 tile, BK=32 (m97 structure).
// EPI=0: ->bf16  EPI=1: gelu->bf16  EPI=2: *0.9+resid ->f32
template <int EPI>
__global__ __launch_bounds__(256, 3) void gemm128(
    const short* __restrict__ A, const short* __restrict__ Bt,
    const float* __restrict__ bias, short* __restrict__ out_bf,
    float* __restrict__ out_f, const float* __restrict__ resid,
    int M, int N, int K) {
  alignas(16) __shared__ short a_lds[128 * 32];
  alignas(16) __shared__ short b_lds[128 * 32];
  const int tid = threadIdx.x;
  const int wv = tid >> 6, lane = tid & 63;
  const int wm = wv >> 1, wn = wv & 1;
  const int g = lane >> 4, r = lane & 15;
  const int m0 = blockIdx.x * 128, n0 = blockIdx.y * 128;
  const int srow = lane >> 2, sseg = lane & 3;
  f32x4 acc[4][4] = {};
  const short* aptr = A + (size_t)(m0 + wv * 16 + srow) * K + sseg * 8;
  const short* bptr = Bt + (size_t)(n0 + wv * 16 + srow) * K + sseg * 8;
  short* alds0 = &a_lds[(wv * 16) * 32];
  short* blds0 = &b_lds[(wv * 16) * 32];
  for (int k0 = 0; k0 < K; k0 += 32) {
    __syncthreads();
    gll16(aptr + k0, alds0);
    gll16(aptr + k0 + (size_t)64 * K, alds0 + 64 * 32);
    gll16(bptr + k0, blds0);
    gll16(bptr + k0 + (size_t)64 * K, blds0 + 64 * 32);
    __syncthreads();
    bf16x8 af[4], bfr[4];
#pragma unroll
    for (int i = 0; i < 4; ++i)
      af[i] = *reinterpret_cast<const bf16x8*>(&a_lds[(wm * 64 + i * 16 + r) * 32 + g * 8]);
#pragma unroll
    for (int i = 0; i < 4; ++i)
      bfr[i] = *reinterpret_cast<const bf16x8*>(&b_lds[(wn * 64 + i * 16 + r) * 32 + g * 8]);
#pragma unroll
    for (int i = 0; i < 4; ++i)
#pragma unroll
      for (int jn = 0; jn < 4; ++jn)
        acc[i][jn] = __builtin_amdgcn_mfma_f32_16x16x32_bf16(af[i], bfr[jn], acc[i][jn], 0, 0, 0);
  }
#pragma unroll
  for (int i = 0; i < 4; ++i) {
#pragma unroll
    for (int jn = 0; jn < 4; ++jn) {
      int col = n0 + wn * 64 + jn * 16 + r;
      float bb = bias[col];
#pragma unroll
      for (int jj = 0; jj < 4; ++jj) {
        int row = m0 + wm * 64 + i * 16 + g * 4 + jj;
        float v = acc[i][jn][jj] + bb;
        size_t idx = (size_t)row * N + col;
        if (EPI == 0) {
          out_bf[idx] = f2bf(v);
        } else if (EPI == 1) {
          v = 0.5f * v * (1.0f + erff(v * 0.70710678118654752f));
          out_bf[idx] = f2bf(v);
        } else {
          out_f[idx] = v * 0.9f + resid[idx];
        }
      }
    }
  }
}

// Flash attention: grid (P/128, B*H). 4 waves, each owns 32 q rows (2 m-frags).
// Swapped QK^T (S^T = mfma(K,Q)): each lane owns 16 k-scores of ONE q row ->
// softmax reduce is 15 local ops + 2 shfl_xor. P^T written lane-locally (b64
// packed) into the same [q][k] p_lds layout the PV A-frag reads use.
__global__ __launch_bounds__(256, 3) void attn_kernel(const short* __restrict__ qkv,
                                                      const float* __restrict__ x,
                                                      float* __restrict__ x2) {
  alignas(16) __shared__ short k_lds[64 * 72];
  alignas(16) __shared__ short vt_lds[64 * 64];
  alignas(16) __shared__ short p_lds[4][32 * 72];
  const int tid = threadIdx.x, wv = tid >> 6, lane = tid & 63;
  const int g = lane >> 4, r = lane & 15;
  const int b = blockIdx.y / H_, h = blockIdx.y % H_;
  const int TD = 3 * D_;
  const int qrow0 = blockIdx.x * 128 + wv * 32;
  // Q fragments with 1/sqrt(hd)=0.125 folded in (exact: power-of-2 scale in bf16)
  bf16x8 qf[2][2];
#pragma unroll
  for (int mf = 0; mf < 2; ++mf)
#pragma unroll
    for (int kb = 0; kb < 2; ++kb) {
      bf16x8 q = *reinterpret_cast<const bf16x8*>(
          qkv + (size_t)(b * P_ + qrow0 + mf * 16 + r) * TD + h * 64 + kb * 32 + g * 8);
#pragma unroll
      for (int e = 0; e < 8; ++e) q[e] = f2bf(bf2f(q[e]) * 0.125f);
      qf[mf][kb] = q;
    }
  f32x4 acc[2][4] = {};
  float m_run[2], l_run[2];
#pragma unroll
  for (int mf = 0; mf < 2; ++mf) { m_run[mf] = -1e30f; l_run[mf] = 0.0f; }
  const int lrow = tid >> 2, lseg = tid & 3;
  short* p_w = &p_lds[wv][0];
  const int bcast = 20 * g;  // src lane 16*g + (4*g + j): holds q-row r=4g+j
  for (int kc = 0; kc < P_; kc += 64) {
    // prefetch K/V rows to registers before the barrier (overlap with prev compute)
    const short* src = qkv + (size_t)(b * P_ + kc + lrow) * TD + D_ + h * 64 + lseg * 16;
    bf16x8 kv0 = *reinterpret_cast<const bf16x8*>(src);
    bf16x8 kv1 = *reinterpret_cast<const bf16x8*>(src + 8);
    bf16x8 vv0 = *reinterpret_cast<const bf16x8*>(src + D_);
    bf16x8 vv1 = *reinterpret_cast<const bf16x8*>(src + D_ + 8);
    __syncthreads();
    *reinterpret_cast<bf16x8*>(&k_lds[lrow * 72 + lseg * 16]) = kv0;
    *reinterpret_cast<bf16x8*>(&k_lds[lrow * 72 + lseg * 16 + 8]) = kv1;
#pragma unroll
    for (int j = 0; j < 8; ++j) {
      int d0 = lseg * 16 + j, d1 = d0 + 8;
      vt_lds[d0 * 64 + (lrow ^ vswz(d0))] = vv0[j];
      vt_lds[d1 * 64 + (lrow ^ vswz(d1))] = vv1[j];
    }
    __syncthreads();
    // swapped QK^T -> S^T: lane holds S[q = mf*16+r][k = cf*16 + 4g + j]
    f32x4 st[2][4];
#pragma unroll
    for (int cf = 0; cf < 4; ++cf) {
      bf16x8 kf0 = *reinterpret_cast<const bf16x8*>(&k_lds[(cf * 16 + r) * 72 + g * 8]);
      bf16x8 kf1 = *reinterpret_cast<const bf16x8*>(&k_lds[(cf * 16 + r) * 72 + 32 + g * 8]);
#pragma unroll
      for (int mf = 0; mf < 2; ++mf) {
        f32x4 s = {};
        s = __builtin_amdgcn_mfma_f32_16x16x32_bf16(kf0, qf[mf][0], s, 0, 0, 0);
        s = __builtin_amdgcn_mfma_f32_16x16x32_bf16(kf1, qf[mf][1], s, 0, 0, 0);
        st[mf][cf] = s;
      }
    }
    // lane-local online softmax
#pragma unroll
    for (int mf = 0; mf < 2; ++mf) {
      float mx = st[mf][0][0];
#pragma unroll
      for (int cf = 0; cf < 4; ++cf)
#pragma unroll
        for (int j = 0; j < 4; ++j) mx = fmaxf(mx, st[mf][cf][j]);
      mx = fmaxf(mx, __shfl_xor(mx, 16, 64));
      mx = fmaxf(mx, __shfl_xor(mx, 32, 64));
      float mn = fmaxf(m_run[mf], mx);
      float corr = __expf(m_run[mf] - mn);
      m_run[mf] = mn;
      float p[4][4];
      float ls = 0.0f;
#pragma unroll
      for (int cf = 0; cf < 4; ++cf)
#pragma unroll
        for (int j = 0; j < 4; ++j) {
          float pv = __expf(st[mf][cf][j] - mn);
          p[cf][j] = pv;
          ls += pv;
        }
      ls += __shfl_xor(ls, 16, 64);
      ls += __shfl_xor(ls, 32, 64);
      l_run[mf] = l_run[mf] * corr + ls;
      // write P^T row (q = mf*16 + r), packed pairs, b64 per cf
      short* prow = &p_w[(mf * 16 + r) * 72];
#pragma unroll
      for (int cf = 0; cf < 4; ++cf) {
        __hip_bfloat162 lo = __float22bfloat162_rn(make_float2(p[cf][0], p[cf][1]));
        __hip_bfloat162 hi = __float22bfloat162_rn(make_float2(p[cf][2], p[cf][3]));
        union { __hip_bfloat162 h2; unsigned u; } c0, c1;
        c0.h2 = lo; c1.h2 = hi;
        *reinterpret_cast<uint2*>(&prow[cf * 16 + 4 * g]) = make_uint2(c0.u, c1.u);
      }
      // broadcast corr to the acc layout (acc row q = mf*16 + 4g + j)
      float cb0 = __shfl(corr, bcast + 0, 64);
      float cb1 = __shfl(corr, bcast + 1, 64);
      float cb2 = __shfl(corr, bcast + 2, 64);
      float cb3 = __shfl(corr, bcast + 3, 64);
#pragma unroll
      for (int cf = 0; cf < 4; ++cf) {
        acc[mf][cf][0] *= cb0; acc[mf][cf][1] *= cb1;
        acc[mf][cf][2] *= cb2; acc[mf][cf][3] *= cb3;
      }
    }
    // PV: vector V fragments from swizzled vt_lds (unchanged)
    bf16x8 vf[4][2];
#pragma unroll
    for (int cf = 0; cf < 4; ++cf) {
      int d = cf * 16 + r;
      int sw = vswz(d);
      vf[cf][0] = *reinterpret_cast<const bf16x8*>(&vt_lds[d * 64 + ((g * 8) ^ sw)]);
      vf[cf][1] = *reinterpret_cast<const bf16x8*>(&vt_lds[d * 64 + ((32 + g * 8) ^ sw)]);
    }
#pragma unroll
    for (int mf = 0; mf < 2; ++mf) {
      bf16x8 pf0 = *reinterpret_cast<const bf16x8*>(&p_w[(mf * 16 + r) * 72 + g * 8]);
      bf16x8 pf1 = *reinterpret_cast<const bf16x8*>(&p_w[(mf * 16 + r) * 72 + 32 + g * 8]);
#pragma unroll
      for (int cf = 0; cf < 4; ++cf) {
        acc[mf][cf] = __builtin_amdgcn_mfma_f32_16x16x32_bf16(pf0, vf[cf][0], acc[mf][cf], 0, 0, 0);
        acc[mf][cf] = __builtin_amdgcn_mfma_f32_16x16x32_bf16(pf1, vf[cf][1], acc[mf][cf], 0, 0, 0);
      }
    }
  }
#pragma unroll
  for (int mf = 0; mf < 2; ++mf) {
    float lb0 = 0.9f / __shfl(l_run[mf], bcast + 0, 64);
    float lb1 = 0.9f / __shfl(l_run[mf], bcast + 1, 64);
    float lb2 = 0.9f / __shfl(l_run[mf], bcast + 2, 64);
    float lb3 = 0.9f / __shfl(l_run[mf], bcast + 3, 64);
    float lb[4] = {lb0, lb1, lb2, lb3};
#pragma unroll
    for (int cf = 0; cf < 4; ++cf) {
      int col = h * 64 + cf * 16 + r;
#pragma unroll
      for (int j = 0; j < 4; ++j) {
        int row = qrow0 + mf * 16 + g * 4 + j;
        size_t idx = (size_t)(b * P_ + row) * D_ + col;
        x2[idx] = acc[mf][cf][j] * lb[j] + x[idx];
      }
    }
  }
}

extern "C" void kernel_launch(void* const* d_in, const int* in_sizes, int n_in,
                              void* d_out, int out_size, void* d_ws, size_t ws_size,
                              hipStream_t stream) {
  const float* x     = (const float*)d_in[0];
  const float* ln1_g = (const float*)d_in[1];
  const float* ln1_b = (const float*)d_in[2];
  const float* w_qkv = (const float*)d_in[3];
  const float* b_qkv = (const float*)d_in[4];
  const float* ln2_g = (const float*)d_in[5];
  const float* ln2_b = (const float*)d_in[6];
  const float* w1    = (const float*)d_in[7];
  const float* b1    = (const float*)d_in[8];
  const float* w2    = (const float*)d_in[9];
  const float* b2    = (const float*)d_in[10];
  float* out = (float*)d_out;
  char* ws = (char*)d_ws;

  short* wqkv_t = (short*)(ws);                 // [2304][768]  = 3,538,944 B
  short* w1_t   = (short*)(ws + 3538944);       // [3072][768]  = 4,718,592 B
  short* w2_t   = (short*)(ws + 8257536);       // [768][3072]  = 4,718,592 B
  short* h_bf   = (short*)(ws + 12976128);      // [8192][768]  = 12,582,912 B
  short* qkv_bf = (short*)(ws + 25559040);      // [8192][2304] = 37,748,736 B
  short* a1_bf  = qkv_bf;                       // reused: [8192][3072] = 50,331,648 B

  const int R = B_ * P_;  // 8192 rows

  { dim3 g2(768 / 32, 2304 / 32);  tcvt_kernel<<<g2, 256, 0, stream>>>(w_qkv, wqkv_t, 768, 2304); }
  { dim3 g2(768 / 32, 3072 / 32);  tcvt_kernel<<<g2, 256, 0, stream>>>(w1, w1_t, 768, 3072); }
  { dim3 g2(3072 / 32, 768 / 32);  tcvt_kernel<<<g2, 256, 0, stream>>>(w2, w2_t, 3072, 768); }

  ln_kernel<<<R, 256, 0, stream>>>(x, ln1_g, ln1_b, h_bf);

  {
    dim3 grid(R / 128, 2304 / 128);
    gemm128<0><<<grid, 256, 0, stream>>>(h_bf, wqkv_t, b_qkv, qkv_bf, nullptr, nullptr,
                                         R, 2304, 768);
  }
  {
    dim3 grid(P_ / 128, B_ * H_);
    attn_kernel<<<grid, 256, 0, stream>>>(qkv_bf, x, out);
  }
  ln_kernel<<<R, 256, 0, stream>>>(out, ln2_g, ln2_b, h_bf);
  {
    dim3 grid(R / 128, 3072 / 128);
    gemm128<1><<<grid, 256, 0, stream>>>(h_bf, w1_t, b1, a1_bf, nullptr, nullptr,
                                         R, 3072, 768);
  }
  {
    dim3 grid(R / 128, 768 / 128);
    gemm128<2><<<grid, 256, 0, stream>>>(a1_bf, w2_t, b2, nullptr, out, out,
                                         R, 768, 3072);
  }
}